// Round 2
// baseline (324.031 us; speedup 1.0000x reference)
//
#include <hip/hip_runtime.h>
#include <math.h>

#define BATCH 256
#define VOCAB 128000
#define V4 (VOCAB / 4)
#define NTHREADS 1024
#define NT NTHREADS
#define NWAVES (NTHREADS / 64)

typedef float vfloat4 __attribute__((ext_vector_type(4)));

// Round-2 rationale:
//  - R0 (per-elem serial chain) and R1 (chunk-parallel) ran at IDENTICAL speed
//    with VALUBusy 35-37%, HBM 34% -> neither VALU- nor BW-bound. The shared
//    structural property: loads issued and consumed in the SAME iteration, so
//    the vmcnt wait exposes ~full HBM latency every iteration (Little's law:
//    2.77 TB/s = 4.5 B/cy/CU = ~1KB in flight/wave at ~900cy latency).
//  - Fix: explicit depth-2 software pipeline in BOTH phases. Iteration i
//    issues loads for i+1 and computes on data loaded at i-1. 4 vector loads
//    (4KB/wave) in flight continuously. VGPRs are free (grid==CU count, cap
//    128 at 1024 thr/block, we were at 36).
//  - Merge step: branch on (cm > gv) -> common path is 1 exp, not 2.
__global__ __launch_bounds__(NTHREADS) void sampler_kernel(
    const float* __restrict__ logits,
    const float* __restrict__ temps,
    const float* __restrict__ noise,
    float* __restrict__ out_tokens,
    float* __restrict__ out_probs)
{
    const int b    = blockIdx.x;
    const int tid  = threadIdx.x;
    const int wave = tid >> 6;
    const int lane = tid & 63;

    const float t      = temps[b];
    const float safe_t = (t == 0.0f) ? 1.0f : t;
    const float inv_t  = 1.0f / safe_t;

    const vfloat4* lg4 = (const vfloat4*)(logits + (size_t)b * VOCAB);
    const vfloat4* nz4 = (const vfloat4*)(noise  + (size_t)b * VOCAB);
    vfloat4*       pb4 = (vfloat4*)(out_probs + (size_t)b * VOCAB);

    // ---------------- Phase 1: one pass over logits + noise.
    //   gv/gi : max raw logit + first argmax (greedy) [== softmax max, inv_t>0]
    //   s     : sum of exp((x - gv) * inv_t)
    //   sv/si : max of (x*inv_t + gumbel) + first index (sample)
    float gv0 = -INFINITY, gv1 = -INFINITY;
    int   gi0 = 0,          gi1 = 0;
    float s0  = 0.0f,       s1  = 0.0f;
    float sv0 = -INFINITY,  sv1 = -INFINITY;
    int   si0 = 0,          si1 = 0;

    auto proc1 = [&](const vfloat4 x4, const vfloat4 u4, int idx0,
                     float& gv, int& gi, float& s, float& sv, int& si) {
        // chunk max + first-occurrence argmax (independent tree)
        float v01 = fmaxf(x4[0], x4[1]);
        int   i01 = (x4[1] > x4[0]) ? idx0 + 1 : idx0;
        float v23 = fmaxf(x4[2], x4[3]);
        int   i23 = (x4[3] > x4[2]) ? idx0 + 3 : idx0 + 2;
        float cm  = fmaxf(v01, v23);
        int   cmi = (v23 > v01) ? i23 : i01;

        // 4 independent exps vs chunk max (exponents <= 0: no overflow)
        float e0 = __expf((x4[0] - cm) * inv_t);
        float e1 = __expf((x4[1] - cm) * inv_t);
        float e2 = __expf((x4[2] - cm) * inv_t);
        float e3 = __expf((x4[3] - cm) * inv_t);
        float cs = (e0 + e1) + (e2 + e3);

        // online merge; common (late-loop) path costs 1 exp
        if (cm > gv) {
            s = s * __expf((gv - cm) * inv_t) + cs;
            gv = cm; gi = cmi;                 // strict '>' keeps first index
        } else {
            s += cs * __expf((cm - gv) * inv_t);
        }

        // Gumbel-max: z = x*inv_t + (-log(-log(u)))  (same op order as ref)
        float g0 = -__logf(-__logf(u4[0]));
        float g1 = -__logf(-__logf(u4[1]));
        float g2 = -__logf(-__logf(u4[2]));
        float g3 = -__logf(-__logf(u4[3]));
        float z0 = x4[0] * inv_t + g0;
        float z1 = x4[1] * inv_t + g1;
        float z2 = x4[2] * inv_t + g2;
        float z3 = x4[3] * inv_t + g3;
        float w01 = fmaxf(z0, z1);
        int   j01 = (z1 > z0) ? idx0 + 1 : idx0;
        float w23 = fmaxf(z2, z3);
        int   j23 = (z3 > z2) ? idx0 + 3 : idx0 + 2;
        float wm  = fmaxf(w01, w23);
        int   wmi = (w23 > w01) ? j23 : j01;
        if (wm > sv) { si = wmi; sv = wm; }
    };

    // depth-2 software pipeline: loads for round k+1 issue while computing
    // round k-1's data. Invariant at loop top: xa/ua valid @i, xb/ub @i+NT.
    int i = tid;
    vfloat4 xa = lg4[i];
    vfloat4 xb = lg4[i + NT];
    vfloat4 ua = __builtin_nontemporal_load(&nz4[i]);
    vfloat4 ub = __builtin_nontemporal_load(&nz4[i + NT]);
    for (; i + 3 * NT < V4; i += 2 * NT) {
        vfloat4 xc = lg4[i + 2 * NT];
        vfloat4 xd = lg4[i + 3 * NT];
        vfloat4 uc = __builtin_nontemporal_load(&nz4[i + 2 * NT]);
        vfloat4 ud = __builtin_nontemporal_load(&nz4[i + 3 * NT]);
        proc1(xa, ua, 4 * i,        gv0, gi0, s0, sv0, si0);
        proc1(xb, ub, 4 * (i + NT), gv1, gi1, s1, sv1, si1);
        xa = xc; xb = xd; ua = uc; ub = ud;
    }
    // drain: pipelined pair, then at most one unpipelined round
    proc1(xa, ua, 4 * i,        gv0, gi0, s0, sv0, si0);
    proc1(xb, ub, 4 * (i + NT), gv1, gi1, s1, sv1, si1);
    {
        int i2 = i + 2 * NT;
        if (i2 < V4) {
            vfloat4 xc = lg4[i2];
            vfloat4 uc = __builtin_nontemporal_load(&nz4[i2]);
            proc1(xc, uc, 4 * i2, gv0, gi0, s0, sv0, si0);
        }
    }

    // merge set1 into set0 (both sets saw >=14 chunks: all finite)
    {
        float mn = fmaxf(gv0, gv1);
        s0 = s0 * __expf((gv0 - mn) * inv_t) + s1 * __expf((gv1 - mn) * inv_t);
        if (gv1 > gv0 || (gv1 == gv0 && gi1 < gi0)) gi0 = gi1;
        gv0 = mn;
        if (sv1 > sv0 || (sv1 == sv0 && si1 < si0)) { sv0 = sv1; si0 = si1; }
    }

    // wave-level reduction (64 lanes)
#pragma unroll
    for (int off = 32; off >= 1; off >>= 1) {
        float gv2 = __shfl_down(gv0, off);
        int   gi2 = __shfl_down(gi0, off);
        float s2  = __shfl_down(s0,  off);
        float sv2 = __shfl_down(sv0, off);
        int   si2 = __shfl_down(si0, off);
        float mn = fmaxf(gv0, gv2);
        s0 = s0 * __expf((gv0 - mn) * inv_t) + s2 * __expf((gv2 - mn) * inv_t);
        if (gv2 > gv0 || (gv2 == gv0 && gi2 < gi0)) gi0 = gi2;
        gv0 = mn;
        if (sv2 > sv0 || (sv2 == sv0 && si2 < si0)) { sv0 = sv2; si0 = si2; }
    }

    __shared__ float sh_gv[NWAVES], sh_s[NWAVES], sh_sv[NWAVES];
    __shared__ int   sh_gi[NWAVES], sh_si[NWAVES];
    __shared__ float bGV, binvS;
    if (lane == 0) {
        sh_gv[wave] = gv0; sh_s[wave] = s0; sh_gi[wave] = gi0;
        sh_sv[wave] = sv0; sh_si[wave] = si0;
    }
    __syncthreads();
    if (tid == 0) {
        float GVr = sh_gv[0], S = sh_s[0], SV = sh_sv[0];
        int   GI  = sh_gi[0], SI = sh_si[0];
        for (int w = 1; w < NWAVES; ++w) {
            float mn = fmaxf(GVr, sh_gv[w]);
            S = S * __expf((GVr - mn) * inv_t) + sh_s[w] * __expf((sh_gv[w] - mn) * inv_t);
            if (sh_gv[w] > GVr || (sh_gv[w] == GVr && sh_gi[w] < GI)) GI = sh_gi[w];
            GVr = mn;
            if (sh_sv[w] > SV || (sh_sv[w] == SV && sh_si[w] < SI)) { SV = sh_sv[w]; SI = sh_si[w]; }
        }
        bGV = GVr; binvS = 1.0f / S;     // S >= 1 (max element contributes 1)
        out_tokens[b] = (float)((t == 0.0f) ? GI : SI);
    }
    __syncthreads();
    const float Msc  = bGV * inv_t;      // softmax max in scaled domain
    const float invS = binvS;

    // ---------------- Phase 2: streaming probs write; logits re-read is
    // L3-warm. Same depth-2 pipeline.
    int k = tid;
    vfloat4 ya = lg4[k];
    vfloat4 yb = lg4[k + NT];
    for (; k + 3 * NT < V4; k += 2 * NT) {
        vfloat4 yc = lg4[k + 2 * NT];
        vfloat4 yd = lg4[k + 3 * NT];
        vfloat4 pa, pb;
#pragma unroll
        for (int j = 0; j < 4; ++j)
            pa[j] = __expf(fmaf(ya[j], inv_t, -Msc)) * invS;
#pragma unroll
        for (int j = 0; j < 4; ++j)
            pb[j] = __expf(fmaf(yb[j], inv_t, -Msc)) * invS;
        __builtin_nontemporal_store(pa, &pb4[k]);
        __builtin_nontemporal_store(pb, &pb4[k + NT]);
        ya = yc; yb = yd;
    }
    {
        vfloat4 pa, pb;
#pragma unroll
        for (int j = 0; j < 4; ++j)
            pa[j] = __expf(fmaf(ya[j], inv_t, -Msc)) * invS;
#pragma unroll
        for (int j = 0; j < 4; ++j)
            pb[j] = __expf(fmaf(yb[j], inv_t, -Msc)) * invS;
        __builtin_nontemporal_store(pa, &pb4[k]);
        __builtin_nontemporal_store(pb, &pb4[k + NT]);
        int k2 = k + 2 * NT;
        if (k2 < V4) {
            vfloat4 yc = lg4[k2];
            vfloat4 pc;
#pragma unroll
            for (int j = 0; j < 4; ++j)
                pc[j] = __expf(fmaf(yc[j], inv_t, -Msc)) * invS;
            __builtin_nontemporal_store(pc, &pb4[k2]);
        }
    }
}

extern "C" void kernel_launch(void* const* d_in, const int* in_sizes, int n_in,
                              void* d_out, int out_size, void* d_ws, size_t ws_size,
                              hipStream_t stream) {
    const float* logits = (const float*)d_in[0];
    const float* temps  = (const float*)d_in[1];
    const float* noise  = (const float*)d_in[2];
    float* out = (float*)d_out;
    // d_out layout: [tokens (BATCH floats)] [probs (BATCH*VOCAB floats)]
    sampler_kernel<<<BATCH, NTHREADS, 0, stream>>>(logits, temps, noise,
                                                   out, out + BATCH);
}